// Round 7
// baseline (260.997 us; speedup 1.0000x reference)
//
#include <hip/hip_runtime.h>
#include <hip/hip_bf16.h>

typedef __bf16 bf16;
typedef __bf16 bf16x2 __attribute__((ext_vector_type(2)));
typedef __bf16 bf16x8 __attribute__((ext_vector_type(8)));
typedef float f32x4 __attribute__((ext_vector_type(4)));

#define MFMA16(a, b, c) __builtin_amdgcn_mfma_f32_16x16x32_bf16(a, b, c, 0, 0, 0)

// 0.125 (1/sqrt(DK)) * log2(e): folded into Q projection so attention uses exp2.
#define QSCALE 0.18033688f

// async global->LDS, 16B per lane; lds dest = wave-uniform base + lane*16
#define GLOAD_LDS(g, l)                                              \
  __builtin_amdgcn_global_load_lds(                                  \
      (const __attribute__((address_space(1))) void*)(g),            \
      (__attribute__((address_space(3))) void*)(l), 16, 0, 0)

// ---------------------------------------------------------------------------
// Convert q,k,v f32 -> bf16 (one array per blockIdx.y). 8 elems/thread.
// ---------------------------------------------------------------------------
__global__ __launch_bounds__(256) void convert_k(const float* __restrict__ q,
                                                 const float* __restrict__ k,
                                                 const float* __restrict__ v,
                                                 bf16* __restrict__ qb,
                                                 bf16* __restrict__ kb,
                                                 bf16* __restrict__ vb) {
  const float* src = blockIdx.y == 0 ? q : blockIdx.y == 1 ? k : v;
  bf16* dst = blockIdx.y == 0 ? qb : blockIdx.y == 1 ? kb : vb;
  const size_t i = ((size_t)blockIdx.x * 256 + threadIdx.x) * 8;
  float4 a = *(const float4*)(src + i);
  float4 b = *(const float4*)(src + i + 4);
  bf16x8 o;
  o[0] = (bf16)a.x; o[1] = (bf16)a.y; o[2] = (bf16)a.z; o[3] = (bf16)a.w;
  o[4] = (bf16)b.x; o[5] = (bf16)b.y; o[6] = (bf16)b.z; o[7] = (bf16)b.w;
  *(bf16x8*)(dst + i) = o;
}

// ---------------------------------------------------------------------------
// Transpose + f32->bf16 convert the four weight matrices [1024,1024].
// Wt[n][k] = W[k][n].  grid (16,16,4), block 256.
// ---------------------------------------------------------------------------
__global__ __launch_bounds__(256) void transpose_w(const float* __restrict__ w0,
                                                   const float* __restrict__ w1,
                                                   const float* __restrict__ w2,
                                                   const float* __restrict__ w3,
                                                   bf16* __restrict__ dst) {
  __shared__ bf16 T[64][68];
  const float* W = blockIdx.z == 0 ? w0 : blockIdx.z == 1 ? w1
                   : blockIdx.z == 2 ? w2 : w3;
  bf16* Y = dst + (size_t)blockIdx.z * 1024 * 1024;
  const int t = threadIdx.x, r = t >> 2, c4 = t & 3;
  const int k0 = blockIdx.y * 64, n0 = blockIdx.x * 64;

  const float4* src = (const float4*)(W + (size_t)(k0 + r) * 1024 + n0 + c4 * 16);
  float4 f0 = src[0], f1 = src[1], f2 = src[2], f3 = src[3];
  bf16* row = &T[r][c4 * 16];
  row[0] = (bf16)f0.x; row[1] = (bf16)f0.y; row[2] = (bf16)f0.z; row[3] = (bf16)f0.w;
  row[4] = (bf16)f1.x; row[5] = (bf16)f1.y; row[6] = (bf16)f1.z; row[7] = (bf16)f1.w;
  row[8] = (bf16)f2.x; row[9] = (bf16)f2.y; row[10] = (bf16)f2.z; row[11] = (bf16)f2.w;
  row[12] = (bf16)f3.x; row[13] = (bf16)f3.y; row[14] = (bf16)f3.z; row[15] = (bf16)f3.w;
  __syncthreads();

  bf16x8 o0, o1;
#pragma unroll
  for (int j = 0; j < 8; ++j) o0[j] = T[c4 * 16 + j][r];
#pragma unroll
  for (int j = 0; j < 8; ++j) o1[j] = T[c4 * 16 + 8 + j][r];
  bf16* d = Y + (size_t)(n0 + r) * 1024 + k0 + c4 * 16;
  *(bf16x8*)d = o0;
  *(bf16x8*)(d + 8) = o1;
}

// ---------------------------------------------------------------------------
// GEMM, m97 structure: (MT*32)x128 tile, BK=32, 4 waves each (MT*16)x64,
// global_load_lds width-16 staging, unpadded 64B LDS rows.
// QKV=1 (MT=4): fused Q/K/V projection — blockIdx.z selects operands.
//   z=0: Q -> Qp [B,H,S,DK] scaled by QSCALE; z=1: K -> Kp [B,H,S,DK];
//   z=2: V -> Vtp [B,H,DK,S] via in-LDS tile transpose (coalesced stores).
// QKV=0 (MT=2): O projection — xq * Wt + bq -> Yf row-major f32; 64-row
//   tiles -> 512 blocks = 2/CU for wave-level overlap.
// ---------------------------------------------------------------------------
template <int QKV, int MT>
__global__ __launch_bounds__(256) void gemm128(
    const bf16* __restrict__ xq, const bf16* __restrict__ xk,
    const bf16* __restrict__ xv, const bf16* __restrict__ Wt,
    const float* __restrict__ bq, const float* __restrict__ bk,
    const float* __restrict__ bv, bf16* __restrict__ Qp,
    bf16* __restrict__ Kp, bf16* __restrict__ Vtp, float* __restrict__ Yf) {
  __shared__ bf16 Al[MT * 32 * 32];  // MT*32 rows x 32 k
  __shared__ bf16 Bl[128 * 32];      // 8 KB

  const int z = QKV ? blockIdx.z : 0;
  const bf16* X = QKV ? (z == 0 ? xq : z == 1 ? xk : xv) : xq;
  const bf16* Bt = Wt + (size_t)z * 1048576;
  const float* bias = QKV ? (z == 0 ? bq : z == 1 ? bk : bv) : bq;
  const float escale = (QKV && z == 0) ? QSCALE : 1.0f;

  const int t = threadIdx.x;
  const int wave = t >> 6, lane = t & 63, quad = lane >> 4, l16 = lane & 15;
  const int wm = (wave >> 1) * (MT * 16), wn = (wave & 1) * 64;
  const int bm = blockIdx.y * (MT * 32), bn = blockIdx.x * 128;

  // staging: byte offset within a 4 KB stage chunk = wave*1024 + lane*16
  const int off = wave * 1024 + lane * 16;
  const int srow = off >> 6;          // 0..63 (64B per row, BK=32 bf16)
  const int scol = (off & 63) >> 1;   // elem col 0..31
  const bf16* gA0 = X + (size_t)(bm + srow) * 1024 + scol;
  const bf16* gA1 = X + (size_t)(bm + 64 + srow) * 1024 + scol;
  const bf16* gB0 = Bt + (size_t)(bn + srow) * 1024 + scol;
  const bf16* gB1 = Bt + (size_t)(bn + 64 + srow) * 1024 + scol;
  bf16* ldsA0 = Al + wave * 512;  // uniform per wave (elems)
  bf16* ldsA1 = Al + 2048 + wave * 512;
  bf16* ldsB0 = Bl + wave * 512;
  bf16* ldsB1 = Bl + 2048 + wave * 512;

  f32x4 acc[MT][4] = {};

  for (int kb = 0; kb < 1024; kb += 32) {
    GLOAD_LDS(gA0 + kb, ldsA0);
    if (MT == 4) GLOAD_LDS(gA1 + kb, ldsA1);
    GLOAD_LDS(gB0 + kb, ldsB0);
    GLOAD_LDS(gB1 + kb, ldsB1);
    __syncthreads();

    bf16x8 af[MT], bfr[4];
#pragma unroll
    for (int mt = 0; mt < MT; ++mt)
      af[mt] = *(const bf16x8*)(Al + (wm + mt * 16 + l16) * 32 + quad * 8);
#pragma unroll
    for (int nt = 0; nt < 4; ++nt)
      bfr[nt] = *(const bf16x8*)(Bl + (wn + nt * 16 + l16) * 32 + quad * 8);
#pragma unroll
    for (int mt = 0; mt < MT; ++mt)
#pragma unroll
      for (int nt = 0; nt < 4; ++nt)
        acc[mt][nt] = MFMA16(af[mt], bfr[nt], acc[mt][nt]);
    __syncthreads();
  }

  if (QKV && z == 2) {
    // ---- V^T epilogue: in-LDS transpose, coalesced stores ----
    // Tt[ln][m]: 64 n-cols x 128 m-rows, stride 136 (bank stride 4 -> 2-way)
    __shared__ bf16 Tt[64 * 136];
    const int b = bm >> 11;  // 128-row tile never crosses batch boundary
#pragma unroll
    for (int half = 0; half < 2; ++half) {
      if ((wave & 1) == half) {  // waves with wn == half*64 own this n-half
#pragma unroll
        for (int nt = 0; nt < 4; ++nt) {
          const int ln = nt * 16 + l16;  // local n 0..63
          const float bia = bias[bn + half * 64 + ln];
#pragma unroll
          for (int mt = 0; mt < 4; ++mt)
#pragma unroll
            for (int r = 0; r < 4; ++r) {
              const int m = wm + mt * 16 + quad * 4 + r;  // 0..127
              Tt[ln * 136 + m] = (bf16)(acc[mt][nt][r] + bia);
            }
        }
      }
      __syncthreads();
      // store 64 rows x 128 elems: thread -> row t>>2, 32-elem segment
      {
        const int ln = t >> 2, seg = (t & 3) * 32;
        const int gn = bn + half * 64 + ln;
        const int h = gn >> 6, dk = gn & 63;
        const int s0 = (bm & 2047) + seg;
        bf16* dst = Vtp + ((size_t)(b * 16 + h) * 64 + dk) * 2048 + s0;
        const bf16* srcp = Tt + ln * 136 + seg;
#pragma unroll
        for (int j = 0; j < 4; ++j)
          *(bf16x8*)(dst + j * 8) = *(const bf16x8*)(srcp + j * 8);
      }
      __syncthreads();
    }
  } else {
    // ---- regular epilogue. C/D layout: row = quad*4 + r, col = l16 ----
#pragma unroll
    for (int mt = 0; mt < MT; ++mt)
#pragma unroll
      for (int nt = 0; nt < 4; ++nt) {
        const int gn = bn + wn + nt * 16 + l16;
        const float bia = bias[gn];
#pragma unroll
        for (int r = 0; r < 4; ++r) {
          const int gm = bm + wm + mt * 16 + quad * 4 + r;
          const float val = (acc[mt][nt][r] + bia) * escale;
          if (!QKV) {
            Yf[(size_t)gm * 1024 + gn] = val;
          } else {
            const int b = gm >> 11, s = gm & 2047;  // S = 2048
            const int h = gn >> 6, dk = gn & 63;    // DK = 64
            bf16* Y = (z == 0) ? Qp : Kp;
            Y[((size_t)(b * 16 + h) * 2048 + s) * 64 + dk] = (bf16)val;
          }
        }
      }
  }
}

// ---------------------------------------------------------------------------
// Flash attention, causal, no-running-max (scores bounded; exp2 exact in f32),
// row sums via ones-column MFMA. Q pre-scaled by 0.125*log2e.
// Q,K: [B,H,S,64]; Vt: [B,H,64,S]; X out: [B,S,1024] bf16.
// Block = 4 waves, handles q-tile PAIR {x, 31-x} (64 rows each) sequentially
// -> every block does exactly 33 key-tile iterations (perfect balance).
// 64-key K/V tiles staged in LDS (padded stride 72), shared by all 4 waves;
// full-coverage staging: 256 threads x 32 B (two bf16x8) per matrix.
// Next tile's global loads prefetched into registers during compute.
// ---------------------------------------------------------------------------
__global__ __launch_bounds__(256) void attn_k(const bf16* __restrict__ Q,
                                              const bf16* __restrict__ K,
                                              const bf16* __restrict__ Vt,
                                              bf16* __restrict__ X) {
  __shared__ bf16 Kl[64 * 72];      // K[key][d]
  __shared__ bf16 Vl[64 * 72];      // Vt[d][key]
  __shared__ bf16 Pb[4][16 * 72];   // per-wave P tile

  const int t = threadIdx.x;
  const int wave = t >> 6, lane = t & 63, quad = lane >> 4, l16 = lane & 15;
  const int pairx = blockIdx.x, bh = blockIdx.y;
  const int b = bh >> 4, h = bh & 15;

  const bf16* Qb = Q + (size_t)bh * 2048 * 64;
  const bf16* Kb = K + (size_t)bh * 2048 * 64;
  const bf16* Vb = Vt + (size_t)bh * 64 * 2048;

  const int srow = t >> 2;          // 0..63
  const int scol = (t & 3) * 16;    // elem col {0,16,32,48}; 16 elems/thread

  bf16x8 onesf;
#pragma unroll
  for (int i = 0; i < 8; ++i) onesf[i] = (bf16)1.0f;

  bf16* Pw = Pb[wave];

  for (int phase = 0; phase < 2; ++phase) {
    const int qtile = phase ? (31 - pairx) : pairx;
    const int ntiles = qtile + 1;
    const int q0 = qtile * 64 + wave * 16;

    bf16x8 qf0 = *(const bf16x8*)(Qb + (q0 + l16) * 64 + quad * 8);
    bf16x8 qf1 = *(const bf16x8*)(Qb + (q0 + l16) * 64 + 32 + quad * 8);

    f32x4 o[4] = {};
    f32x4 o4 = {};

    // prologue: stage tile 0 (full rows: 2 x bf16x8 per thread per matrix)
    {
      const bf16* kp = Kb + srow * 64 + scol;
      const bf16* vp = Vb + (size_t)srow * 2048 + scol;
      bf16x8 k0r = *(const bf16x8*)kp;
      bf16x8 k1r = *(const bf16x8*)(kp + 8);
      bf16x8 v0r = *(const bf16x8*)vp;
      bf16x8 v1r = *(const bf16x8*)(vp + 8);
      *(bf16x8*)(Kl + srow * 72 + scol) = k0r;
      *(bf16x8*)(Kl + srow * 72 + scol + 8) = k1r;
      *(bf16x8*)(Vl + srow * 72 + scol) = v0r;
      *(bf16x8*)(Vl + srow * 72 + scol + 8) = v1r;
    }
    __syncthreads();

    for (int kt = 0; kt < ntiles; ++kt) {
      const int k0 = kt * 64;
      const bool more = (kt + 1) < ntiles;
      bf16x8 kr0, kr1, vr0, vr1;
      if (more) {  // prefetch next tile (global latency overlapped by compute)
        const bf16* kp = Kb + (k0 + 64 + srow) * 64 + scol;
        const bf16* vp = Vb + (size_t)srow * 2048 + k0 + 64 + scol;
        kr0 = *(const bf16x8*)kp;
        kr1 = *(const bf16x8*)(kp + 8);
        vr0 = *(const bf16x8*)vp;
        vr1 = *(const bf16x8*)(vp + 8);
      }

      // ---- QK^T: 4 n-tiles of 16 keys, 2 d-chunks each ----
      f32x4 sc[4];
#pragma unroll
      for (int nt = 0; nt < 4; ++nt) {
        bf16x8 kf0 = *(const bf16x8*)(Kl + (nt * 16 + l16) * 72 + quad * 8);
        bf16x8 kf1 = *(const bf16x8*)(Kl + (nt * 16 + l16) * 72 + 32 + quad * 8);
        f32x4 s = {};
        s = MFMA16(qf0, kf0, s);
        s = MFMA16(qf1, kf1, s);
        sc[nt] = s;
      }

      // ---- softmax (no max) + P store ----
#pragma unroll
      for (int r = 0; r < 4; ++r) {
        const int row = quad * 4 + r;
        const int qg = q0 + row;
#pragma unroll
        for (int nt = 0; nt < 4; ++nt) {
          const int key = k0 + nt * 16 + l16;
          const float p = (key <= qg) ? exp2f(sc[nt][r]) : 0.f;
          Pw[row * 72 + nt * 16 + l16] = (bf16)p;
        }
      }
      __builtin_amdgcn_s_waitcnt(0xC07F);  // lgkmcnt(0): P visible to wave

      // ---- PV + row sums ----
      bf16x8 pf0 = *(const bf16x8*)(Pw + l16 * 72 + quad * 8);
      bf16x8 pf1 = *(const bf16x8*)(Pw + l16 * 72 + 32 + quad * 8);
      o4 = MFMA16(pf0, onesf, o4);
      o4 = MFMA16(pf1, onesf, o4);
#pragma unroll
      for (int dt = 0; dt < 4; ++dt) {
        bf16x8 vf0 = *(const bf16x8*)(Vl + (dt * 16 + l16) * 72 + quad * 8);
        bf16x8 vf1 = *(const bf16x8*)(Vl + (dt * 16 + l16) * 72 + 32 + quad * 8);
        o[dt] = MFMA16(pf0, vf0, o[dt]);
        o[dt] = MFMA16(pf1, vf1, o[dt]);
      }

      __syncthreads();  // all waves done reading Kl/Vl
      if (more) {
        *(bf16x8*)(Kl + srow * 72 + scol) = kr0;
        *(bf16x8*)(Kl + srow * 72 + scol + 8) = kr1;
        *(bf16x8*)(Vl + srow * 72 + scol) = vr0;
        *(bf16x8*)(Vl + srow * 72 + scol + 8) = vr1;
        __syncthreads();
      }
    }

    // epilogue: normalize + store [B,S,1024]
#pragma unroll
    for (int r = 0; r < 4; ++r) {
      const float rinv = 1.0f / o4[r];
      const int qg = q0 + quad * 4 + r;
#pragma unroll
      for (int dt = 0; dt < 4; ++dt) {
        const int col = h * 64 + dt * 16 + l16;
        X[((size_t)b * 2048 + qg) * 1024 + col] = (bf16)(o[dt][r] * rinv);
      }
    }
    __syncthreads();  // before next phase overwrites Kl/Vl
  }
}

// ---------------------------------------------------------------------------
extern "C" void kernel_launch(void* const* d_in, const int* in_sizes, int n_in,
                              void* d_out, int out_size, void* d_ws,
                              size_t ws_size, hipStream_t stream) {
  const float* q = (const float*)d_in[0];
  const float* k = (const float*)d_in[1];
  const float* v = (const float*)d_in[2];
  const float* w_q = (const float*)d_in[4];
  const float* b_q = (const float*)d_in[5];
  const float* w_k = (const float*)d_in[6];
  const float* b_k = (const float*)d_in[7];
  const float* w_v = (const float*)d_in[8];
  const float* b_v = (const float*)d_in[9];
  const float* w_o = (const float*)d_in[10];
  const float* b_o = (const float*)d_in[11];

  bf16* ws = (bf16*)d_ws;
  const size_t NELEM = (size_t)4096 * 1024;
  bf16* Qp = ws;                // [B,H,S,DK]
  bf16* Kp = ws + NELEM;        // [B,H,S,DK]
  bf16* Vtp = ws + 2 * NELEM;   // [B,H,DK,S]
  bf16* Xp = ws + 3 * NELEM;    // [B,S,D] attn out; doubles as qb before attn
  bf16* Wt = ws + 4 * NELEM;    // 4 x [1024,1024] transposed bf16 weights
  bf16* Wto = Wt + 3145728;
  // converted bf16 inputs: qb aliases Xp (consumed before attn writes Xp);
  // kb/vb live in d_out (16 MB f32 = 2*NELEM bf16; fully overwritten at end)
  bf16* qb = Xp;
  bf16* kb = (bf16*)d_out;
  bf16* vb = kb + NELEM;

  convert_k<<<dim3(2048, 3), 256, 0, stream>>>(q, k, v, qb, kb, vb);
  transpose_w<<<dim3(16, 16, 4), 256, 0, stream>>>(w_q, w_k, w_v, w_o, Wt);

  // fused Q/K/V projections: 8x32x3 = 768 blocks (~3/CU)
  gemm128<1, 4><<<dim3(8, 32, 3), 256, 0, stream>>>(
      qb, kb, vb, Wt, b_q, b_k, b_v, Qp, Kp, Vtp, nullptr);
  attn_k<<<dim3(16, 32), 256, 0, stream>>>(Qp, Kp, Vtp, Xp);
  // O projection: 64-row tiles -> 512 blocks (2/CU)
  gemm128<0, 2><<<dim3(8, 64), 256, 0, stream>>>(
      Xp, nullptr, nullptr, Wto, b_o, nullptr, nullptr, nullptr, nullptr,
      nullptr, (float*)d_out);
}

// Round 8
// 243.920 us; speedup vs baseline: 1.0700x; 1.0700x over previous
//
#include <hip/hip_runtime.h>
#include <hip/hip_bf16.h>

typedef __bf16 bf16;
typedef __bf16 bf16x2 __attribute__((ext_vector_type(2)));
typedef __bf16 bf16x8 __attribute__((ext_vector_type(8)));
typedef float f32x4 __attribute__((ext_vector_type(4)));

#define MFMA16(a, b, c) __builtin_amdgcn_mfma_f32_16x16x32_bf16(a, b, c, 0, 0, 0)

// 0.125 (1/sqrt(DK)) * log2(e): folded into Q projection so attention uses exp2.
#define QSCALE 0.18033688f

// ---------------------------------------------------------------------------
// Convert q,k,v f32 -> bf16 (one array per blockIdx.y). 8 elems/thread.
// ---------------------------------------------------------------------------
__global__ __launch_bounds__(256) void convert_k(const float* __restrict__ q,
                                                 const float* __restrict__ k,
                                                 const float* __restrict__ v,
                                                 bf16* __restrict__ qb,
                                                 bf16* __restrict__ kb,
                                                 bf16* __restrict__ vb) {
  const float* src = blockIdx.y == 0 ? q : blockIdx.y == 1 ? k : v;
  bf16* dst = blockIdx.y == 0 ? qb : blockIdx.y == 1 ? kb : vb;
  const size_t i = ((size_t)blockIdx.x * 256 + threadIdx.x) * 8;
  float4 a = *(const float4*)(src + i);
  float4 b = *(const float4*)(src + i + 4);
  bf16x8 o;
  o[0] = (bf16)a.x; o[1] = (bf16)a.y; o[2] = (bf16)a.z; o[3] = (bf16)a.w;
  o[4] = (bf16)b.x; o[5] = (bf16)b.y; o[6] = (bf16)b.z; o[7] = (bf16)b.w;
  *(bf16x8*)(dst + i) = o;
}

// ---------------------------------------------------------------------------
// Transpose + f32->bf16 convert the four weight matrices [1024,1024].
// Wt[n][k] = W[k][n].  grid (16,16,4), block 256.
// ---------------------------------------------------------------------------
__global__ __launch_bounds__(256) void transpose_w(const float* __restrict__ w0,
                                                   const float* __restrict__ w1,
                                                   const float* __restrict__ w2,
                                                   const float* __restrict__ w3,
                                                   bf16* __restrict__ dst) {
  __shared__ bf16 T[64][68];
  const float* W = blockIdx.z == 0 ? w0 : blockIdx.z == 1 ? w1
                   : blockIdx.z == 2 ? w2 : w3;
  bf16* Y = dst + (size_t)blockIdx.z * 1024 * 1024;
  const int t = threadIdx.x, r = t >> 2, c4 = t & 3;
  const int k0 = blockIdx.y * 64, n0 = blockIdx.x * 64;

  const float4* src = (const float4*)(W + (size_t)(k0 + r) * 1024 + n0 + c4 * 16);
  float4 f0 = src[0], f1 = src[1], f2 = src[2], f3 = src[3];
  bf16* row = &T[r][c4 * 16];
  row[0] = (bf16)f0.x; row[1] = (bf16)f0.y; row[2] = (bf16)f0.z; row[3] = (bf16)f0.w;
  row[4] = (bf16)f1.x; row[5] = (bf16)f1.y; row[6] = (bf16)f1.z; row[7] = (bf16)f1.w;
  row[8] = (bf16)f2.x; row[9] = (bf16)f2.y; row[10] = (bf16)f2.z; row[11] = (bf16)f2.w;
  row[12] = (bf16)f3.x; row[13] = (bf16)f3.y; row[14] = (bf16)f3.z; row[15] = (bf16)f3.w;
  __syncthreads();

  bf16x8 o0, o1;
#pragma unroll
  for (int j = 0; j < 8; ++j) o0[j] = T[c4 * 16 + j][r];
#pragma unroll
  for (int j = 0; j < 8; ++j) o1[j] = T[c4 * 16 + 8 + j][r];
  bf16* d = Y + (size_t)(n0 + r) * 1024 + k0 + c4 * 16;
  *(bf16x8*)d = o0;
  *(bf16x8*)(d + 8) = o1;
}

// ---------------------------------------------------------------------------
// Pipelined GEMM: (MT*32)x128 tile, BK=64, register-prefetch staging
// (next tile's global loads in flight during current tile's MFMA compute).
// LDS rows padded to stride 72 (2-way on frag b128 reads = free).
// QKV=1 (MT=4): fused Q/K/V projection, z selects operands.
//   z=0: Q -> Qp [B,H,S,DK] scaled; z=1: K -> Kp; z=2: V -> Vtp [B,H,DK,S]
//   via in-LDS transpose (Tt aliases Al).
// QKV=0 (MT=2): O projection -> Yf row-major f32 (512 blocks = 2/CU).
// ---------------------------------------------------------------------------
template <int QKV, int MT>
__global__ __launch_bounds__(256, 3) void gemm_p(
    const bf16* __restrict__ xq, const bf16* __restrict__ xk,
    const bf16* __restrict__ xv, const bf16* __restrict__ Wt,
    const float* __restrict__ bq, const float* __restrict__ bk,
    const float* __restrict__ bv, bf16* __restrict__ Qp,
    bf16* __restrict__ Kp, bf16* __restrict__ Vtp, float* __restrict__ Yf) {
  constexpr int AROWS = MT * 32;
  __shared__ bf16 Al[AROWS * 72];
  __shared__ bf16 Bl[128 * 72];

  const int z = QKV ? blockIdx.z : 0;
  const bf16* X = QKV ? (z == 0 ? xq : z == 1 ? xk : xv) : xq;
  const bf16* Bt = Wt + (size_t)z * 1048576;
  const float* bias = QKV ? (z == 0 ? bq : z == 1 ? bk : bv) : bq;
  const float escale = (QKV && z == 0) ? QSCALE : 1.0f;

  const int t = threadIdx.x;
  const int wave = t >> 6, lane = t & 63, quad = lane >> 4, l16 = lane & 15;
  const int wm = (wave >> 1) * (MT * 16), wn = (wave & 1) * 64;
  const int bm = blockIdx.y * AROWS, bn = blockIdx.x * 128;

  // staging assignment (contiguous chunks, fully covering each tile):
  // A: MT*32 rows x 64 k  -> MT*8 elems/thread; B: 128 x 64 -> 32 elems/thread
  constexpr int NA = (MT == 4) ? 4 : 2;
  const int arow = (MT == 4) ? (t >> 1) : (t >> 2);
  const int acol = (MT == 4) ? ((t & 1) * 32) : ((t & 3) * 16);
  const int brow = t >> 1, bcol = (t & 1) * 32;
  const bf16* gA = X + (size_t)(bm + arow) * 1024 + acol;
  const bf16* gB = Bt + (size_t)(bn + brow) * 1024 + bcol;

  bf16x8 ra[NA], rb[4];
#pragma unroll
  for (int j = 0; j < NA; ++j) ra[j] = *(const bf16x8*)(gA + j * 8);
#pragma unroll
  for (int j = 0; j < 4; ++j) rb[j] = *(const bf16x8*)(gB + j * 8);

  f32x4 acc[MT][4] = {};

  for (int kb = 0; kb < 1024; kb += 64) {
    __syncthreads();  // all waves done reading previous tile
#pragma unroll
    for (int j = 0; j < NA; ++j)
      *(bf16x8*)(Al + arow * 72 + acol + j * 8) = ra[j];
#pragma unroll
    for (int j = 0; j < 4; ++j)
      *(bf16x8*)(Bl + brow * 72 + bcol + j * 8) = rb[j];
    __syncthreads();

    if (kb + 64 < 1024) {  // prefetch next tile; lands during compute below
#pragma unroll
      for (int j = 0; j < NA; ++j)
        ra[j] = *(const bf16x8*)(gA + kb + 64 + j * 8);
#pragma unroll
      for (int j = 0; j < 4; ++j)
        rb[j] = *(const bf16x8*)(gB + kb + 64 + j * 8);
    }

#pragma unroll
    for (int kk = 0; kk < 2; ++kk) {
      bf16x8 af[MT], bfr[4];
#pragma unroll
      for (int mt = 0; mt < MT; ++mt)
        af[mt] =
            *(const bf16x8*)(Al + (wm + mt * 16 + l16) * 72 + kk * 32 + quad * 8);
#pragma unroll
      for (int nt = 0; nt < 4; ++nt)
        bfr[nt] =
            *(const bf16x8*)(Bl + (wn + nt * 16 + l16) * 72 + kk * 32 + quad * 8);
#pragma unroll
      for (int mt = 0; mt < MT; ++mt)
#pragma unroll
        for (int nt = 0; nt < 4; ++nt)
          acc[mt][nt] = MFMA16(af[mt], bfr[nt], acc[mt][nt]);
    }
  }

  if (QKV && z == 2) {
    // ---- V^T epilogue: in-LDS transpose (Tt aliases Al), coalesced stores
    bf16* Tt = Al;  // 64*136 = 8704 elems <= AROWS*72 = 9216
    const int b = bm >> 11;
    __syncthreads();  // everyone done with Al before reuse
#pragma unroll
    for (int half = 0; half < 2; ++half) {
      if ((wave & 1) == half) {
#pragma unroll
        for (int nt = 0; nt < 4; ++nt) {
          const int ln = nt * 16 + l16;
          const float bia = bias[bn + half * 64 + ln];
#pragma unroll
          for (int mt = 0; mt < 4; ++mt)
#pragma unroll
            for (int r = 0; r < 4; ++r) {
              const int m = wm + mt * 16 + quad * 4 + r;
              Tt[ln * 136 + m] = (bf16)(acc[mt][nt][r] + bia);
            }
        }
      }
      __syncthreads();
      {
        const int ln = t >> 2, seg = (t & 3) * 32;
        const int gn = bn + half * 64 + ln;
        const int h = gn >> 6, dk = gn & 63;
        const int s0 = (bm & 2047) + seg;
        bf16* dstp = Vtp + ((size_t)(b * 16 + h) * 64 + dk) * 2048 + s0;
        const bf16* srcp = Tt + ln * 136 + seg;
#pragma unroll
        for (int j = 0; j < 4; ++j)
          *(bf16x8*)(dstp + j * 8) = *(const bf16x8*)(srcp + j * 8);
      }
      __syncthreads();
    }
  } else {
    // ---- regular epilogue. C/D layout: row = quad*4 + r, col = l16 ----
#pragma unroll
    for (int mt = 0; mt < MT; ++mt)
#pragma unroll
      for (int nt = 0; nt < 4; ++nt) {
        const int gn = bn + wn + nt * 16 + l16;
        const float bia = bias[gn];
#pragma unroll
        for (int r = 0; r < 4; ++r) {
          const int gm = bm + wm + mt * 16 + quad * 4 + r;
          const float val = (acc[mt][nt][r] + bia) * escale;
          if (!QKV) {
            Yf[(size_t)gm * 1024 + gn] = val;
          } else {
            const int b = gm >> 11, s = gm & 2047;  // S = 2048
            const int h = gn >> 6, dk = gn & 63;    // DK = 64
            bf16* Y = (z == 0) ? Qp : Kp;
            Y[((size_t)(b * 16 + h) * 2048 + s) * 64 + dk] = (bf16)val;
          }
        }
      }
  }
}

// ---------------------------------------------------------------------------
// Flash attention, causal, no-running-max, row sums via ones-column MFMA.
// Q pre-scaled by 0.125*log2e. Q,K: [B,H,S,64]; Vt: [B,H,64,S]; X: [B,S,1024].
// Block = q-tile PAIR {x, 31-x} -> exactly 33 key-tile iterations per block.
// K LDS rows PERMUTED (key kk -> row (kk&32) + (kk&1)*16 + ((kk&31)>>1)) so
// score n-tile (g,p) lane l16 holds key g*32 + 2*l16 + p: P columns become
// key-identity -> packed bf16x2 P writes; V layout unchanged.
// Interior tiles (k0+63 <= q0) skip the causal mask entirely (wave-uniform).
// ---------------------------------------------------------------------------
__global__ __launch_bounds__(256) void attn_k(const bf16* __restrict__ Q,
                                              const bf16* __restrict__ K,
                                              const bf16* __restrict__ Vt,
                                              bf16* __restrict__ X) {
  __shared__ bf16 Kl[64 * 72];      // K rows permuted
  __shared__ bf16 Vl[64 * 72];      // Vt[d][key]
  __shared__ bf16 Pb[4][16 * 72];   // per-wave P tile (cols = key order)

  const int t = threadIdx.x;
  const int wave = t >> 6, lane = t & 63, quad = lane >> 4, l16 = lane & 15;
  const int pairx = blockIdx.x, bh = blockIdx.y;
  const int b = bh >> 4, h = bh & 15;

  const bf16* Qb = Q + (size_t)bh * 2048 * 64;
  const bf16* Kb = K + (size_t)bh * 2048 * 64;
  const bf16* Vb = Vt + (size_t)bh * 64 * 2048;

  const int srow = t >> 2;          // 0..63 (key for K, d for V)
  const int scol = (t & 3) * 16;    // elem col {0,16,32,48}
  // permuted K destination row for key srow:
  const int crow = (srow & 32) + ((srow & 1) << 4) + ((srow & 31) >> 1);

  bf16x8 onesf;
#pragma unroll
  for (int i = 0; i < 8; ++i) onesf[i] = (bf16)1.0f;

  bf16* Pw = Pb[wave];

  for (int phase = 0; phase < 2; ++phase) {
    const int qtile = phase ? (31 - pairx) : pairx;
    const int ntiles = qtile + 1;
    const int q0 = qtile * 64 + wave * 16;

    bf16x8 qf0 = *(const bf16x8*)(Qb + (q0 + l16) * 64 + quad * 8);
    bf16x8 qf1 = *(const bf16x8*)(Qb + (q0 + l16) * 64 + 32 + quad * 8);

    f32x4 o[4] = {};
    f32x4 o4 = {};

    // prologue: stage tile 0
    {
      const bf16* kp = Kb + srow * 64 + scol;
      const bf16* vp = Vb + (size_t)srow * 2048 + scol;
      bf16x8 k0r = *(const bf16x8*)kp;
      bf16x8 k1r = *(const bf16x8*)(kp + 8);
      bf16x8 v0r = *(const bf16x8*)vp;
      bf16x8 v1r = *(const bf16x8*)(vp + 8);
      *(bf16x8*)(Kl + crow * 72 + scol) = k0r;
      *(bf16x8*)(Kl + crow * 72 + scol + 8) = k1r;
      *(bf16x8*)(Vl + srow * 72 + scol) = v0r;
      *(bf16x8*)(Vl + srow * 72 + scol + 8) = v1r;
    }
    __syncthreads();

    for (int kt = 0; kt < ntiles; ++kt) {
      const int k0 = kt * 64;
      const bool more = (kt + 1) < ntiles;
      bf16x8 kr0, kr1, vr0, vr1;
      if (more) {  // prefetch next tile
        const bf16* kp = Kb + (k0 + 64 + srow) * 64 + scol;
        const bf16* vp = Vb + (size_t)srow * 2048 + k0 + 64 + scol;
        kr0 = *(const bf16x8*)kp;
        kr1 = *(const bf16x8*)(kp + 8);
        vr0 = *(const bf16x8*)vp;
        vr1 = *(const bf16x8*)(vp + 8);
      }

      // ---- QK^T: n-tile nt=(g<<1)|p, lane l16 <-> key k0+g*32+2*l16+p ----
      f32x4 sc[4];
#pragma unroll
      for (int nt = 0; nt < 4; ++nt) {
        bf16x8 kf0 = *(const bf16x8*)(Kl + (nt * 16 + l16) * 72 + quad * 8);
        bf16x8 kf1 = *(const bf16x8*)(Kl + (nt * 16 + l16) * 72 + 32 + quad * 8);
        f32x4 s = {};
        s = MFMA16(qf0, kf0, s);
        s = MFMA16(qf1, kf1, s);
        sc[nt] = s;
      }

      // ---- softmax + packed P store (cols key-identity) ----
      const bool interior = (k0 + 63) <= q0;  // wave-uniform
#pragma unroll
      for (int r = 0; r < 4; ++r) {
        const int row = quad * 4 + r;
        float e0 = exp2f(sc[0][r]);  // key k0 + 2*l16
        float e1 = exp2f(sc[1][r]);  // key k0 + 2*l16 + 1
        float e2 = exp2f(sc[2][r]);  // key k0 + 32 + 2*l16
        float e3 = exp2f(sc[3][r]);  // key k0 + 32 + 2*l16 + 1
        if (!interior) {
          const int qg = q0 + row;
          const int key0 = k0 + 2 * l16;
          if (key0 > qg) e0 = 0.f;
          if (key0 + 1 > qg) e1 = 0.f;
          if (key0 + 32 > qg) e2 = 0.f;
          if (key0 + 33 > qg) e3 = 0.f;
        }
        bf16x2 p01, p23;
        p01[0] = (bf16)e0; p01[1] = (bf16)e1;
        p23[0] = (bf16)e2; p23[1] = (bf16)e3;
        *(bf16x2*)(Pw + row * 72 + 2 * l16) = p01;
        *(bf16x2*)(Pw + row * 72 + 32 + 2 * l16) = p23;
      }
      __builtin_amdgcn_s_waitcnt(0xC07F);  // lgkmcnt(0): P visible to wave

      // ---- PV + row sums (P cols and Vl cols both key-ordered) ----
      bf16x8 pf0 = *(const bf16x8*)(Pw + l16 * 72 + quad * 8);
      bf16x8 pf1 = *(const bf16x8*)(Pw + l16 * 72 + 32 + quad * 8);
      o4 = MFMA16(pf0, onesf, o4);
      o4 = MFMA16(pf1, onesf, o4);
#pragma unroll
      for (int dt = 0; dt < 4; ++dt) {
        bf16x8 vf0 = *(const bf16x8*)(Vl + (dt * 16 + l16) * 72 + quad * 8);
        bf16x8 vf1 = *(const bf16x8*)(Vl + (dt * 16 + l16) * 72 + 32 + quad * 8);
        o[dt] = MFMA16(pf0, vf0, o[dt]);
        o[dt] = MFMA16(pf1, vf1, o[dt]);
      }

      __syncthreads();  // all waves done reading Kl/Vl
      if (more) {
        *(bf16x8*)(Kl + crow * 72 + scol) = kr0;
        *(bf16x8*)(Kl + crow * 72 + scol + 8) = kr1;
        *(bf16x8*)(Vl + srow * 72 + scol) = vr0;
        *(bf16x8*)(Vl + srow * 72 + scol + 8) = vr1;
        __syncthreads();
      }
    }

    // epilogue: normalize + store [B,S,1024]
#pragma unroll
    for (int r = 0; r < 4; ++r) {
      const float rinv = 1.0f / o4[r];
      const int qg = q0 + quad * 4 + r;
#pragma unroll
      for (int dt = 0; dt < 4; ++dt) {
        const int col = h * 64 + dt * 16 + l16;
        X[((size_t)b * 2048 + qg) * 1024 + col] = (bf16)(o[dt][r] * rinv);
      }
    }
    __syncthreads();  // before next phase overwrites Kl/Vl
  }
}

// ---------------------------------------------------------------------------
extern "C" void kernel_launch(void* const* d_in, const int* in_sizes, int n_in,
                              void* d_out, int out_size, void* d_ws,
                              size_t ws_size, hipStream_t stream) {
  const float* q = (const float*)d_in[0];
  const float* k = (const float*)d_in[1];
  const float* v = (const float*)d_in[2];
  const float* w_q = (const float*)d_in[4];
  const float* b_q = (const float*)d_in[5];
  const float* w_k = (const float*)d_in[6];
  const float* b_k = (const float*)d_in[7];
  const float* w_v = (const float*)d_in[8];
  const float* b_v = (const float*)d_in[9];
  const float* w_o = (const float*)d_in[10];
  const float* b_o = (const float*)d_in[11];

  bf16* ws = (bf16*)d_ws;
  const size_t NELEM = (size_t)4096 * 1024;
  bf16* Qp = ws;                // [B,H,S,DK]
  bf16* Kp = ws + NELEM;        // [B,H,S,DK]
  bf16* Vtp = ws + 2 * NELEM;   // [B,H,DK,S]
  bf16* Xp = ws + 3 * NELEM;    // [B,S,D] attn out; doubles as qb before attn
  bf16* Wt = ws + 4 * NELEM;    // 4 x [1024,1024] transposed bf16 weights
  bf16* Wto = Wt + 3145728;
  bf16* qb = Xp;
  bf16* kb = (bf16*)d_out;      // d_out scratch, overwritten by final GEMM
  bf16* vb = kb + NELEM;

  convert_k<<<dim3(2048, 3), 256, 0, stream>>>(q, k, v, qb, kb, vb);
  transpose_w<<<dim3(16, 16, 4), 256, 0, stream>>>(w_q, w_k, w_v, w_o, Wt);

  // fused Q/K/V projections: 8x32x3 = 768 blocks (3/CU)
  gemm_p<1, 4><<<dim3(8, 32, 3), 256, 0, stream>>>(
      qb, kb, vb, Wt, b_q, b_k, b_v, Qp, Kp, Vtp, nullptr);
  attn_k<<<dim3(16, 32), 256, 0, stream>>>(Qp, Kp, Vtp, Xp);
  // O projection: 64-row tiles -> 512 blocks (2/CU)
  gemm_p<0, 2><<<dim3(8, 64), 256, 0, stream>>>(
      Xp, nullptr, nullptr, Wto, b_o, nullptr, nullptr, nullptr, nullptr,
      nullptr, (float*)d_out);
}